// Round 2
// baseline (1526.265 us; speedup 1.0000x reference)
//
#include <hip/hip_runtime.h>
#include <hip/hip_bf16.h>
#include <math.h>

// Problem constants
#define B_   16
#define P_   32
#define N_   1024          // P*P
#define C_   192
#define H_   12
#define HD_  16
#define HID_ 768
#define C3_  576           // 3*C
#define SCALE_ 0.25f       // HD^-0.5

// ---------------------------------------------------------------------------
// K1: transpose x [B,N,C] -> xi [B,C,N]
// grid (6, 32, 16) = (C/32, N/32, B), block (32,8)
__global__ __launch_bounds__(256) void transpose_kernel(const float* __restrict__ x,
                                                        float* __restrict__ xi) {
  __shared__ float tile[32][33];
  int b = blockIdx.z;
  int c0 = blockIdx.x * 32, n0 = blockIdx.y * 32;
  int tx = threadIdx.x, ty = threadIdx.y;
#pragma unroll
  for (int i = 0; i < 4; i++) {
    int n = n0 + ty + i * 8;
    tile[ty + i * 8][tx] = x[((size_t)b * N_ + n) * C_ + c0 + tx];
  }
  __syncthreads();
#pragma unroll
  for (int i = 0; i < 4; i++) {
    int c = c0 + ty + i * 8;
    xi[((size_t)b * C_ + c) * N_ + n0 + tx] = tile[tx][ty + i * 8];
  }
}

// ---------------------------------------------------------------------------
// K2: conv3x3 (192->768, pad 1) + bias + relu.  xi [B,C,N] -> a1 [B,768,N]
// grid (48, 16) = (768/16 oc tiles, B), block 256.
// Each block: 16 oc x full 32x32 image. Each thread: 4 consecutive rows x 1 col.
__global__ __launch_bounds__(256) void conv3x3_kernel(const float* __restrict__ xi,
                                                      const float* __restrict__ w1,
                                                      const float* __restrict__ b1,
                                                      float* __restrict__ a1) {
  __shared__ float s_in[12 * 1024];   // 12 input channels x 32x32
  __shared__ float s_w[16 * 108];     // [oc16][ic12*9]
  int t = threadIdx.x;
  int oc0 = blockIdx.x * 16, b = blockIdx.y;
  int px = t & 31, py0 = (t >> 5) * 4;
  float acc[16][4] = {};

  for (int c0 = 0; c0 < C_; c0 += 12) {
    __syncthreads();
    {
      const float4* src = (const float4*)(xi + ((size_t)(b * C_ + c0)) * N_);
      float4* dst = (float4*)s_in;
#pragma unroll
      for (int i = 0; i < 12; i++) dst[t + i * 256] = src[t + i * 256];
    }
    {
      float4* dst = (float4*)s_w;
#pragma unroll
      for (int i = 0; i < 2; i++) {
        int e4 = t + i * 256;
        if (e4 < 432) {
          int oc = e4 / 27, rem = e4 - oc * 27;
          dst[e4] = ((const float4*)(w1 + (size_t)(oc0 + oc) * 1728 + c0 * 9))[rem];
        }
      }
    }
    __syncthreads();

    for (int ic = 0; ic < 12; ic++) {
      float vals[6][3];
#pragma unroll
      for (int rr = 0; rr < 6; rr++) {
        int row = py0 - 1 + rr;
#pragma unroll
        for (int dx = 0; dx < 3; dx++) {
          int col = px - 1 + dx;
          vals[rr][dx] = (row >= 0 && row < 32 && col >= 0 && col < 32)
                             ? s_in[ic * 1024 + row * 32 + col] : 0.f;
        }
      }
#pragma unroll
      for (int oc = 0; oc < 16; oc++) {
        float w[9];
#pragma unroll
        for (int kk = 0; kk < 9; kk++) w[kk] = s_w[oc * 108 + ic * 9 + kk];
#pragma unroll
        for (int r = 0; r < 4; r++) {
#pragma unroll
          for (int dy = 0; dy < 3; dy++) {
#pragma unroll
            for (int dx = 0; dx < 3; dx++)
              acc[oc][r] += w[dy * 3 + dx] * vals[r + dy][dx];
          }
        }
      }
    }
  }

#pragma unroll
  for (int oc = 0; oc < 16; oc++) {
    float bv = b1[oc0 + oc];
#pragma unroll
    for (int r = 0; r < 4; r++) {
      float v = acc[oc][r] + bv;
      a1[((size_t)(b * HID_ + oc0 + oc)) * N_ + (py0 + r) * 32 + px] = v > 0.f ? v : 0.f;
    }
  }
}

// ---------------------------------------------------------------------------
// K3/K4: 1x1 conv = GEMM.  out[b,oc,n] = act(bias[oc] + sum_ic W[oc,ic]*in[b,ic,n])
// ACT: 0 = relu, 1 = sigmoid.  grid (N/64, OC/64, B), block 256, 4x4 acc/thread.
template <int ACT>
__global__ __launch_bounds__(256) void gemm1x1_kernel(const float* __restrict__ W,
                                                      const float* __restrict__ bias,
                                                      const float* __restrict__ in,
                                                      float* __restrict__ out,
                                                      int OC, int IC) {
  __shared__ float s_w[16 * 68];   // [ic16][oc64] padded
  __shared__ float s_in[16 * 64];  // [ic16][n64]
  int t = threadIdx.x;
  int n0 = blockIdx.x * 64, oc0 = blockIdx.y * 64, b = blockIdx.z;
  int tx = t & 15, ty = t >> 4;
  float acc[4][4] = {};
  const float* inb = in + ((size_t)b * IC) * N_;

  for (int k0 = 0; k0 < IC; k0 += 16) {
    __syncthreads();
    {
      int r = t >> 6, c = t & 63;
#pragma unroll
      for (int i = 0; i < 4; i++)
        s_in[(r + i * 4) * 64 + c] = inb[(size_t)(k0 + r + i * 4) * N_ + n0 + c];
      int oc_l = t >> 4, ic_l = t & 15;
#pragma unroll
      for (int i = 0; i < 4; i++)
        s_w[ic_l * 68 + oc_l + i * 16] = W[(size_t)(oc0 + oc_l + i * 16) * IC + k0 + ic_l];
    }
    __syncthreads();
#pragma unroll
    for (int kk = 0; kk < 16; kk++) {
      float4 av = *(const float4*)&s_w[kk * 68 + ty * 4];
      float4 bv = *(const float4*)&s_in[kk * 64 + tx * 4];
      float ar[4] = {av.x, av.y, av.z, av.w};
      float br[4] = {bv.x, bv.y, bv.z, bv.w};
#pragma unroll
      for (int u = 0; u < 4; u++)
#pragma unroll
        for (int vv = 0; vv < 4; vv++) acc[u][vv] += ar[u] * br[vv];
    }
  }

#pragma unroll
  for (int u = 0; u < 4; u++) {
    int oc = oc0 + ty * 4 + u;
    float bv2 = bias[oc];
    float4 res;
    float r0 = acc[u][0] + bv2, r1 = acc[u][1] + bv2, r2 = acc[u][2] + bv2, r3 = acc[u][3] + bv2;
    if (ACT == 0) {
      res.x = r0 > 0.f ? r0 : 0.f; res.y = r1 > 0.f ? r1 : 0.f;
      res.z = r2 > 0.f ? r2 : 0.f; res.w = r3 > 0.f ? r3 : 0.f;
    } else {
      res.x = 1.f / (1.f + __expf(-r0)); res.y = 1.f / (1.f + __expf(-r1));
      res.z = 1.f / (1.f + __expf(-r2)); res.w = 1.f / (1.f + __expf(-r3));
    }
    *(float4*)&out[((size_t)b * OC + oc) * N_ + n0 + tx * 4] = res;
  }
}

// ---------------------------------------------------------------------------
// K5: gather a3 * y -> q,k,v [B,H,N,HD] with the reference's flat-index scramble.
// j = (g&1023)*192 + (g>>10);  y_flat[j] = x[b, j&1023, j>>10];
// a_{q,k,v} = a3[b, (j+off)%576, (j+off)/576], off = 0 / 196608 / 393216.
__global__ __launch_bounds__(256) void qkv_gather_kernel(const float* __restrict__ a3,
                                                         const float* __restrict__ x,
                                                         float* __restrict__ q,
                                                         float* __restrict__ k,
                                                         float* __restrict__ v) {
  int idx = blockIdx.x * 256 + threadIdx.x;  // [0, B*196608)
  int b = idx / 196608;
  int g = idx - b * 196608;
  int m = g & 1023, cc = g >> 10;
  int j = m * 192 + cc;
  float y = x[((size_t)b * N_ + (j & 1023)) * C_ + (j >> 10)];
  int n2 = g / 192;
  int hd = g - n2 * 192;
  size_t out_idx = (((size_t)b * H_ + (hd >> 4)) * N_ + n2) * HD_ + (hd & 15);
  const float* a3b = a3 + (size_t)b * (C3_ * N_);
  int jk = j + 196608, jv = j + 393216;
  int nq = j / 576,  chq = j - nq * 576;
  int nk = jk / 576, chk = jk - nk * 576;
  int nv = jv / 576, chv = jv - nv * 576;
  float aq = a3b[chq * 1024 + nq];
  float ak = a3b[chk * 1024 + nk];
  float av = a3b[chv * 1024 + nv];
  q[out_idx] = aq * y * SCALE_;
  k[out_idx] = ak * y;
  v[out_idx] = av * y;
}

// ---------------------------------------------------------------------------
// K6: attention per (b,h): softmax(q k^T) v, online softmax, K/V staged in LDS
// in 512-key chunks. grid (2, 12, 16), block 256, 2 rows/thread.
// Writes o directly in [B, N, C] layout (o[b, n, h*16+d]).
__global__ __launch_bounds__(256) void attn_kernel(const float* __restrict__ Q,
                                                   const float* __restrict__ K,
                                                   const float* __restrict__ V,
                                                   float* __restrict__ O) {
  __shared__ float sk[512 * 16];
  __shared__ float sv[512 * 16];
  int t = threadIdx.x;
  int rh = blockIdx.x, h = blockIdx.y, b = blockIdx.z;
  size_t base = ((size_t)(b * H_ + h)) * (N_ * HD_);
  const float* Qg = Q + base;
  const float* Kg = K + base;
  const float* Vg = V + base;
  int r0 = rh * 512 + t * 2;

  float qr[2][16];
#pragma unroll
  for (int r = 0; r < 2; r++) {
    const float4* q4 = (const float4*)(Qg + (size_t)(r0 + r) * HD_);
#pragma unroll
    for (int i = 0; i < 4; i++) {
      float4 tmp = q4[i];
      qr[r][i * 4 + 0] = tmp.x; qr[r][i * 4 + 1] = tmp.y;
      qr[r][i * 4 + 2] = tmp.z; qr[r][i * 4 + 3] = tmp.w;
    }
  }
  float mmax[2] = {-1e30f, -1e30f};
  float lsum[2] = {0.f, 0.f};
  float acc[2][16] = {};

  for (int jc = 0; jc < 2; jc++) {
    __syncthreads();
    const float4* ksrc = (const float4*)(Kg + jc * 8192);
    const float4* vsrc = (const float4*)(Vg + jc * 8192);
    float4* skd = (float4*)sk;
    float4* svd = (float4*)sv;
#pragma unroll
    for (int i = 0; i < 8; i++) {
      skd[t + i * 256] = ksrc[t + i * 256];
      svd[t + i * 256] = vsrc[t + i * 256];
    }
    __syncthreads();

    for (int j = 0; j < 512; j++) {
      float kv[16];
      const float4* kr = (const float4*)(sk + j * 16);
#pragma unroll
      for (int i = 0; i < 4; i++) {
        float4 tmp = kr[i];
        kv[i * 4] = tmp.x; kv[i * 4 + 1] = tmp.y; kv[i * 4 + 2] = tmp.z; kv[i * 4 + 3] = tmp.w;
      }
      float s0 = 0.f, s1 = 0.f;
#pragma unroll
      for (int i = 0; i < 16; i++) { s0 += qr[0][i] * kv[i]; s1 += qr[1][i] * kv[i]; }
      float vv[16];
      const float4* vr = (const float4*)(sv + j * 16);
#pragma unroll
      for (int i = 0; i < 4; i++) {
        float4 tmp = vr[i];
        vv[i * 4] = tmp.x; vv[i * 4 + 1] = tmp.y; vv[i * 4 + 2] = tmp.z; vv[i * 4 + 3] = tmp.w;
      }
      float ss[2] = {s0, s1};
#pragma unroll
      for (int r = 0; r < 2; r++) {
        float s = ss[r];
        if (s > mmax[r]) {
          float corr = __expf(mmax[r] - s);
          lsum[r] *= corr;
#pragma unroll
          for (int i = 0; i < 16; i++) acc[r][i] *= corr;
          mmax[r] = s;
        }
        float p = __expf(s - mmax[r]);
        lsum[r] += p;
#pragma unroll
        for (int i = 0; i < 16; i++) acc[r][i] += p * vv[i];
      }
    }
  }

#pragma unroll
  for (int r = 0; r < 2; r++) {
    float inv = 1.0f / lsum[r];
    float* od = O + ((size_t)(b * N_ + r0 + r)) * C_ + h * HD_;
#pragma unroll
    for (int i = 0; i < 4; i++) {
      float4 tmp;
      tmp.x = acc[r][i * 4 + 0] * inv; tmp.y = acc[r][i * 4 + 1] * inv;
      tmp.z = acc[r][i * 4 + 2] * inv; tmp.w = acc[r][i * 4 + 3] * inv;
      ((float4*)od)[i] = tmp;
    }
  }
}

// ---------------------------------------------------------------------------
// K7: out[m,c] = sum_j o[m,j] * w_out[c,j].  M = B*N = 16384, K = C = 192.
// grid (3, 256) = (C/64, M/64), block 256, 4x4 acc/thread.
__global__ __launch_bounds__(256) void proj_kernel(const float* __restrict__ o,
                                                   const float* __restrict__ wout,
                                                   float* __restrict__ out) {
  __shared__ float s_o[16 * 68];
  __shared__ float s_w[16 * 68];
  int t = threadIdx.x;
  int c0 = blockIdx.x * 64, m0 = blockIdx.y * 64;
  int tx = t & 15, ty = t >> 4;  // tx -> c group, ty -> m group
  float acc[4][4] = {};

  for (int j0 = 0; j0 < C_; j0 += 16) {
    __syncthreads();
    {
      int a_l = t >> 4, j_l = t & 15;
#pragma unroll
      for (int i = 0; i < 4; i++)
        s_o[j_l * 68 + a_l + i * 16] = o[(size_t)(m0 + a_l + i * 16) * C_ + j0 + j_l];
#pragma unroll
      for (int i = 0; i < 4; i++)
        s_w[j_l * 68 + a_l + i * 16] = wout[(size_t)(c0 + a_l + i * 16) * C_ + j0 + j_l];
    }
    __syncthreads();
#pragma unroll
    for (int kk = 0; kk < 16; kk++) {
      float4 av = *(const float4*)&s_o[kk * 68 + ty * 4];
      float4 bv = *(const float4*)&s_w[kk * 68 + tx * 4];
      float ar[4] = {av.x, av.y, av.z, av.w};
      float br[4] = {bv.x, bv.y, bv.z, bv.w};
#pragma unroll
      for (int u = 0; u < 4; u++)
#pragma unroll
        for (int vv = 0; vv < 4; vv++) acc[u][vv] += ar[u] * br[vv];
    }
  }

#pragma unroll
  for (int u = 0; u < 4; u++) {
    int m = m0 + ty * 4 + u;
    float4 res;
    res.x = acc[u][0]; res.y = acc[u][1]; res.z = acc[u][2]; res.w = acc[u][3];
    *(float4*)&out[(size_t)m * C_ + c0 + tx * 4] = res;
  }
}

// ---------------------------------------------------------------------------
extern "C" void kernel_launch(void* const* d_in, const int* in_sizes, int n_in,
                              void* d_out, int out_size, void* d_ws, size_t ws_size,
                              hipStream_t stream) {
  const float* x     = (const float*)d_in[0];
  const float* w1    = (const float*)d_in[1];
  const float* b1    = (const float*)d_in[2];
  const float* w2    = (const float*)d_in[3];
  const float* b2    = (const float*)d_in[4];
  const float* w3    = (const float*)d_in[5];
  const float* b3    = (const float*)d_in[6];
  const float* w_out = (const float*)d_in[7];
  float* out = (float*)d_out;

  // Workspace layout (floats). Total = 28,311,552 floats = ~108 MB.
  float* ws = (float*)d_ws;
  float* xi = ws;                        // 3,145,728  [B,C,N]
  float* R1 = ws + 3145728;              // 12,582,912 (a1 -> a3 -> o)
  float* R2 = R1 + 12582912;             // 12,582,912 (a2 -> q,k,v)
  float* a1 = R1;
  float* a2 = R2;
  float* a3 = R1;                        // overwrites a1 (dead)
  float* q  = R2;                        // overwrites a2 (dead)
  float* k  = R2 + 3145728;
  float* v  = R2 + 6291456;
  float* o  = R1;                        // overwrites a3 (dead)

  transpose_kernel<<<dim3(6, 32, 16), dim3(32, 8), 0, stream>>>(x, xi);
  conv3x3_kernel<<<dim3(48, 16), 256, 0, stream>>>(xi, w1, b1, a1);
  gemm1x1_kernel<0><<<dim3(16, 12, 16), 256, 0, stream>>>(w2, b2, a1, a2, HID_, HID_);
  gemm1x1_kernel<1><<<dim3(16, 9, 16), 256, 0, stream>>>(w3, b3, a2, a3, C3_, HID_);
  qkv_gather_kernel<<<dim3(12288), 256, 0, stream>>>(a3, x, q, k, v);
  attn_kernel<<<dim3(2, 12, 16), 256, 0, stream>>>(q, k, v, o);
  proj_kernel<<<dim3(3, 256), 256, 0, stream>>>(o, w_out, out);
}

// Round 3
// 701.687 us; speedup vs baseline: 2.1751x; 2.1751x over previous
//
#include <hip/hip_runtime.h>
#include <hip/hip_bf16.h>
#include <math.h>

// Problem constants
#define B_   16
#define P_   32
#define N_   1024
#define C_   192
#define H_   12
#define HD_  16
#define HID_ 768
#define C3_  576
#define SCALE_ 0.25f

using u16 = unsigned short;
typedef __bf16 bf16x8 __attribute__((ext_vector_type(8)));
typedef float f32x4 __attribute__((ext_vector_type(4)));
typedef u16 u16x8 __attribute__((ext_vector_type(8)));
typedef u16 u16x4 __attribute__((ext_vector_type(4)));

#define MFMA16(a, b, c) __builtin_amdgcn_mfma_f32_16x16x32_bf16((a), (b), (c), 0, 0, 0)

__device__ __forceinline__ int swz(int r) { return (r + (r >> 2)) & 3; }

__device__ __forceinline__ void splitf(float v, u16& h, u16& l) {
  union { __hip_bfloat16 b; u16 u; } c1, c2;
  c1.b = __float2bfloat16(v);
  float hv = __bfloat162float(c1.b);
  c2.b = __float2bfloat16(v - hv);
  h = c1.u; l = c2.u;
}

// LDS fragment read: tile stored as [row][32 k] u16, 64B rows, chunk-XOR swizzle.
__device__ __forceinline__ bf16x8 ldfrag(const u16* base, int row, int g) {
  return __builtin_bit_cast(bf16x8,
      *(const u16x8*)(base + row * 32 + ((g ^ swz(row)) << 3)));
}

// ---------------------------------------------------------------------------
// Pack x -> zero-padded 34x34 image, [b][pad_pixel][192ch] bf16 hi/lo.
// 8 channels per thread; border pixels written as zero EVERY call (ws is poisoned).
__global__ __launch_bounds__(256) void pack_x_kernel(const float* __restrict__ x,
                                                     u16* __restrict__ xph,
                                                     u16* __restrict__ xpl) {
  int tid = blockIdx.x * 256 + threadIdx.x;   // 16*1156*24 = 443904 total
  int b = tid / 27744;
  int r = tid - b * 27744;
  int pp = r / 24;
  int cg = (r - pp * 24) * 8;
  int pr = pp / 34, pc = pp - pr * 34;
  float v[8] = {0.f, 0.f, 0.f, 0.f, 0.f, 0.f, 0.f, 0.f};
  if (pr >= 1 && pr <= 32 && pc >= 1 && pc <= 32) {
    const float* src = x + ((size_t)b * N_ + (pr - 1) * 32 + (pc - 1)) * C_ + cg;
    float4 v0 = *(const float4*)src;
    float4 v1 = *(const float4*)(src + 4);
    v[0] = v0.x; v[1] = v0.y; v[2] = v0.z; v[3] = v0.w;
    v[4] = v1.x; v[5] = v1.y; v[6] = v1.z; v[7] = v1.w;
  }
  u16x8 vh, vl;
#pragma unroll
  for (int i = 0; i < 8; ++i) { u16 h, l; splitf(v[i], h, l); vh[i] = h; vl[i] = l; }
  size_t o = ((size_t)b * 1156 + pp) * C_ + cg;
  *(u16x8*)&xph[o] = vh;
  *(u16x8*)&xpl[o] = vl;
}

// Pack w1 [768][192][3][3] -> [tap][768][192] hi/lo
__global__ __launch_bounds__(256) void pack_w1_kernel(const float* __restrict__ w1,
                                                      u16* __restrict__ w1h,
                                                      u16* __restrict__ w1l) {
  int tid = blockIdx.x * 256 + threadIdx.x;   // 147456
  int oc = tid / C_, ic = tid - oc * C_;
  const float* src = w1 + ((size_t)oc * C_ + ic) * 9;
#pragma unroll
  for (int t9 = 0; t9 < 9; ++t9) {
    u16 h, l; splitf(src[t9], h, l);
    size_t o = (size_t)t9 * (HID_ * C_) + oc * C_ + ic;
    w1h[o] = h; w1l[o] = l;
  }
}

// Generic elementwise pack (count divisible by 8*256 not required; bounds-checked)
__global__ __launch_bounds__(256) void pack_gen_kernel(const float* __restrict__ src,
                                                       u16* __restrict__ dh,
                                                       u16* __restrict__ dl, int n8) {
  int tid = blockIdx.x * 256 + threadIdx.x;
  if (tid >= n8) return;
  const float* s = src + (size_t)tid * 8;
  float4 v0 = *(const float4*)s;
  float4 v1 = *(const float4*)(s + 4);
  float v[8] = {v0.x, v0.y, v0.z, v0.w, v1.x, v1.y, v1.z, v1.w};
  u16x8 vh, vl;
#pragma unroll
  for (int i = 0; i < 8; ++i) { u16 h, l; splitf(v[i], h, l); vh[i] = h; vl[i] = l; }
  *(u16x8*)&dh[(size_t)tid * 8] = vh;
  *(u16x8*)&dl[(size_t)tid * 8] = vl;
}

// ---------------------------------------------------------------------------
// conv3x3 as implicit GEMM via MFMA. Block: 128oc x 64px, 4 waves (2m x 2n).
// grid (16 px-tiles, 6 oc-tiles, 16 b). Output a1 [b][pixel][768] bf16 hi/lo (relu'd).
__global__ __launch_bounds__(256) void conv_mfma_kernel(
    const u16* __restrict__ xph, const u16* __restrict__ xpl,
    const u16* __restrict__ w1h, const u16* __restrict__ w1l,
    const float* __restrict__ b1, u16* __restrict__ a1h, u16* __restrict__ a1l) {
  __shared__ u16 sA[2][128 * 32];
  __shared__ u16 sB[2][64 * 32];
  int t = threadIdx.x;
  int n0 = blockIdx.x * 64, oc0 = blockIdx.y * 128, b = blockIdx.z;
  int wid = t >> 6, lane = t & 63;
  int wm = wid >> 1, wn = wid & 1;
  int g = lane >> 4, lr = lane & 15;
  f32x4 acc[4][2] = {};

  for (int tap = 0; tap < 9; ++tap) {
    int dy = tap / 3, dx = tap - dy * 3;
    const u16* wth = w1h + (size_t)tap * (HID_ * C_);
    const u16* wtl = w1l + (size_t)tap * (HID_ * C_);
    for (int ks = 0; ks < 6; ++ks) {
      int kk = ks * 32;
      __syncthreads();
      // stage A (weights): 128 rows x 32k, hi+lo
#pragma unroll
      for (int i = 0; i < 2; ++i) {
        int c = t + i * 256;
        int r = c >> 2, p = c & 3;
        size_t gidx = (size_t)(oc0 + r) * C_ + kk + p * 8;
        int lidx = r * 32 + ((p ^ swz(r)) << 3);
        *(u16x8*)&sA[0][lidx] = *(const u16x8*)&wth[gidx];
        *(u16x8*)&sA[1][lidx] = *(const u16x8*)&wtl[gidx];
      }
      // stage B (shifted pixels): 64 rows x 32k, hi+lo
      {
        int c = t;
        int r = c >> 2, p = c & 3;
        int pix = n0 + r;
        int py = pix >> 5, px = pix & 31;
        int pad = (py + dy) * 34 + (px + dx);
        size_t gidx = ((size_t)b * 1156 + pad) * C_ + kk + p * 8;
        int lidx = r * 32 + ((p ^ swz(r)) << 3);
        *(u16x8*)&sB[0][lidx] = *(const u16x8*)&xph[gidx];
        *(u16x8*)&sB[1][lidx] = *(const u16x8*)&xpl[gidx];
      }
      __syncthreads();
      bf16x8 ah[4], al[4], bh[2], bl[2];
#pragma unroll
      for (int mf = 0; mf < 4; ++mf) {
        int row = wm * 64 + mf * 16 + lr;
        ah[mf] = ldfrag(&sA[0][0], row, g);
        al[mf] = ldfrag(&sA[1][0], row, g);
      }
#pragma unroll
      for (int nf = 0; nf < 2; ++nf) {
        int row = wn * 32 + nf * 16 + lr;
        bh[nf] = ldfrag(&sB[0][0], row, g);
        bl[nf] = ldfrag(&sB[1][0], row, g);
      }
#pragma unroll
      for (int mf = 0; mf < 4; ++mf)
#pragma unroll
        for (int nf = 0; nf < 2; ++nf) {
          acc[mf][nf] = MFMA16(ah[mf], bh[nf], acc[mf][nf]);
          acc[mf][nf] = MFMA16(al[mf], bh[nf], acc[mf][nf]);
          acc[mf][nf] = MFMA16(ah[mf], bl[nf], acc[mf][nf]);
        }
    }
  }
  // epilogue: bias + relu + bf16 hi/lo split, write [pixel][oc]
#pragma unroll
  for (int mf = 0; mf < 4; ++mf)
#pragma unroll
    for (int nf = 0; nf < 2; ++nf) {
      int pix = n0 + wn * 32 + nf * 16 + lr;
      int oc = oc0 + wm * 64 + mf * 16 + g * 4;
      size_t oidx = ((size_t)b * N_ + pix) * HID_ + oc;
      u16x4 vh, vl;
#pragma unroll
      for (int r = 0; r < 4; ++r) {
        float v = acc[mf][nf][r] + b1[oc + r];
        v = v > 0.f ? v : 0.f;
        u16 h, l; splitf(v, h, l);
        vh[r] = h; vl[r] = l;
      }
      *(u16x4*)&a1h[oidx] = vh;
      *(u16x4*)&a1l[oidx] = vl;
    }
}

// ---------------------------------------------------------------------------
// Generic MFMA GEMM over [pixel][IC] activations: out = act(W @ in + bias).
// ACT: 0 relu->bf16 hi/lo, 1 sigmoid->f32, 2 none->f32.
// Block tile MT x 64px, 4 waves (2m x 2n). grid (16, OC/MT, 16).
template <int ACT, int MT>
__global__ __launch_bounds__(256) void gemm_mfma_kernel(
    const u16* __restrict__ Wh, const u16* __restrict__ Wl,
    const float* __restrict__ bias,
    const u16* __restrict__ inh, const u16* __restrict__ inl,
    void* __restrict__ out0, void* __restrict__ out1, int OC, int IC) {
  constexpr int MF = MT / 32;
  __shared__ u16 sA[2][MT * 32];
  __shared__ u16 sB[2][64 * 32];
  int t = threadIdx.x;
  int n0 = blockIdx.x * 64, oc0 = blockIdx.y * MT, b = blockIdx.z;
  int wid = t >> 6, lane = t & 63;
  int wm = wid >> 1, wn = wid & 1;
  int g = lane >> 4, lr = lane & 15;
  const u16* inbh = inh + (size_t)b * N_ * IC;
  const u16* inbl = inl + (size_t)b * N_ * IC;
  f32x4 acc[MF][2] = {};

  for (int ks = 0; ks < IC / 32; ++ks) {
    int kk = ks * 32;
    __syncthreads();
    for (int c = t; c < MT * 4; c += 256) {
      int r = c >> 2, p = c & 3;
      size_t gidx = (size_t)(oc0 + r) * IC + kk + p * 8;
      int lidx = r * 32 + ((p ^ swz(r)) << 3);
      *(u16x8*)&sA[0][lidx] = *(const u16x8*)&Wh[gidx];
      *(u16x8*)&sA[1][lidx] = *(const u16x8*)&Wl[gidx];
    }
    {
      int c = t;
      int r = c >> 2, p = c & 3;
      size_t gidx = (size_t)(n0 + r) * IC + kk + p * 8;
      int lidx = r * 32 + ((p ^ swz(r)) << 3);
      *(u16x8*)&sB[0][lidx] = *(const u16x8*)&inbh[gidx];
      *(u16x8*)&sB[1][lidx] = *(const u16x8*)&inbl[gidx];
    }
    __syncthreads();
    bf16x8 ah[MF], al[MF], bh[2], bl[2];
#pragma unroll
    for (int mf = 0; mf < MF; ++mf) {
      int row = wm * (MT / 2) + mf * 16 + lr;
      ah[mf] = ldfrag(&sA[0][0], row, g);
      al[mf] = ldfrag(&sA[1][0], row, g);
    }
#pragma unroll
    for (int nf = 0; nf < 2; ++nf) {
      int row = wn * 32 + nf * 16 + lr;
      bh[nf] = ldfrag(&sB[0][0], row, g);
      bl[nf] = ldfrag(&sB[1][0], row, g);
    }
#pragma unroll
    for (int mf = 0; mf < MF; ++mf)
#pragma unroll
      for (int nf = 0; nf < 2; ++nf) {
        acc[mf][nf] = MFMA16(ah[mf], bh[nf], acc[mf][nf]);
        acc[mf][nf] = MFMA16(al[mf], bh[nf], acc[mf][nf]);
        acc[mf][nf] = MFMA16(ah[mf], bl[nf], acc[mf][nf]);
      }
  }
#pragma unroll
  for (int mf = 0; mf < MF; ++mf)
#pragma unroll
    for (int nf = 0; nf < 2; ++nf) {
      int pix = n0 + wn * 32 + nf * 16 + lr;
      int oc = oc0 + wm * (MT / 2) + mf * 16 + g * 4;
      size_t oidx = ((size_t)b * N_ + pix) * OC + oc;
      if constexpr (ACT == 0) {
        u16x4 vh, vl;
#pragma unroll
        for (int r = 0; r < 4; ++r) {
          float v = acc[mf][nf][r] + bias[oc + r];
          v = v > 0.f ? v : 0.f;
          u16 h, l; splitf(v, h, l);
          vh[r] = h; vl[r] = l;
        }
        *(u16x4*)&((u16*)out0)[oidx] = vh;
        *(u16x4*)&((u16*)out1)[oidx] = vl;
      } else if constexpr (ACT == 1) {
        float4 res;
        float r0 = acc[mf][nf][0] + bias[oc + 0];
        float r1 = acc[mf][nf][1] + bias[oc + 1];
        float r2 = acc[mf][nf][2] + bias[oc + 2];
        float r3 = acc[mf][nf][3] + bias[oc + 3];
        res.x = 1.f / (1.f + __expf(-r0)); res.y = 1.f / (1.f + __expf(-r1));
        res.z = 1.f / (1.f + __expf(-r2)); res.w = 1.f / (1.f + __expf(-r3));
        *(float4*)&((float*)out0)[oidx] = res;
      } else {
        float4 res;
        res.x = acc[mf][nf][0]; res.y = acc[mf][nf][1];
        res.z = acc[mf][nf][2]; res.w = acc[mf][nf][3];
        *(float4*)&((float*)out0)[oidx] = res;
      }
    }
}

// ---------------------------------------------------------------------------
// qkv gather: a3 now [b][pixel][576]. Same flat-index scramble as before.
__global__ __launch_bounds__(256) void qkv_gather_kernel(const float* __restrict__ a3,
                                                         const float* __restrict__ x,
                                                         float* __restrict__ q,
                                                         float* __restrict__ k,
                                                         float* __restrict__ v) {
  int idx = blockIdx.x * 256 + threadIdx.x;
  int b = idx / 196608;
  int gg = idx - b * 196608;
  int m = gg & 1023, cc = gg >> 10;
  int j = m * 192 + cc;
  float y = x[((size_t)b * N_ + (j & 1023)) * C_ + (j >> 10)];
  int n2 = gg / 192;
  int hd = gg - n2 * 192;
  size_t out_idx = (((size_t)b * H_ + (hd >> 4)) * N_ + n2) * HD_ + (hd & 15);
  const float* a3b = a3 + (size_t)b * (C3_ * N_);
  int jk = j + 196608, jv = j + 393216;
  int nq = j / 576,  chq = j - nq * 576;
  int nk = jk / 576, chk = jk - nk * 576;
  int nv = jv / 576, chv = jv - nv * 576;
  float aq = a3b[(size_t)nq * C3_ + chq];
  float ak = a3b[(size_t)nk * C3_ + chk];
  float av = a3b[(size_t)nv * C3_ + chv];
  q[out_idx] = aq * y * SCALE_;
  k[out_idx] = ak * y;
  v[out_idx] = av * y;
}

// ---------------------------------------------------------------------------
// attention: f32 online softmax, 1 row/thread, 256-key LDS chunks.
// grid (4, 12, 16). Output o as bf16 hi/lo in [b][n][192] (h*16+d).
__global__ __launch_bounds__(256) void attn_kernel(const float* __restrict__ Q,
                                                   const float* __restrict__ K,
                                                   const float* __restrict__ V,
                                                   u16* __restrict__ oh,
                                                   u16* __restrict__ ol) {
  __shared__ float sk[256 * 16];
  __shared__ float sv[256 * 16];
  int t = threadIdx.x;
  int rh = blockIdx.x, h = blockIdx.y, b = blockIdx.z;
  size_t base = ((size_t)(b * H_ + h)) * (N_ * HD_);
  const float* Qg = Q + base;
  const float* Kg = K + base;
  const float* Vg = V + base;
  int r0 = rh * 256 + t;

  float qr[16];
  {
    const float4* q4 = (const float4*)(Qg + (size_t)r0 * HD_);
#pragma unroll
    for (int i = 0; i < 4; ++i) {
      float4 tmp = q4[i];
      qr[i * 4 + 0] = tmp.x; qr[i * 4 + 1] = tmp.y;
      qr[i * 4 + 2] = tmp.z; qr[i * 4 + 3] = tmp.w;
    }
  }
  float mmax = -1e30f, lsum = 0.f;
  float acc[16] = {};

  for (int jc = 0; jc < 4; ++jc) {
    __syncthreads();
    const float4* ksrc = (const float4*)(Kg + jc * 4096);
    const float4* vsrc = (const float4*)(Vg + jc * 4096);
    float4* skd = (float4*)sk;
    float4* svd = (float4*)sv;
#pragma unroll
    for (int i = 0; i < 4; ++i) {
      skd[t + i * 256] = ksrc[t + i * 256];
      svd[t + i * 256] = vsrc[t + i * 256];
    }
    __syncthreads();

    for (int j = 0; j < 256; ++j) {
      float kv[16], vv[16];
      const float4* kr = (const float4*)(sk + j * 16);
      const float4* vr = (const float4*)(sv + j * 16);
#pragma unroll
      for (int i = 0; i < 4; ++i) {
        float4 a = kr[i], c = vr[i];
        kv[i * 4] = a.x; kv[i * 4 + 1] = a.y; kv[i * 4 + 2] = a.z; kv[i * 4 + 3] = a.w;
        vv[i * 4] = c.x; vv[i * 4 + 1] = c.y; vv[i * 4 + 2] = c.z; vv[i * 4 + 3] = c.w;
      }
      float s = 0.f;
#pragma unroll
      for (int i = 0; i < 16; ++i) s += qr[i] * kv[i];
      if (s > mmax) {
        float corr = __expf(mmax - s);
        lsum *= corr;
#pragma unroll
        for (int i = 0; i < 16; ++i) acc[i] *= corr;
        mmax = s;
      }
      float p = __expf(s - mmax);
      lsum += p;
#pragma unroll
      for (int i = 0; i < 16; ++i) acc[i] += p * vv[i];
    }
  }

  float inv = 1.0f / lsum;
  size_t o = ((size_t)b * N_ + r0) * C_ + h * HD_;
#pragma unroll
  for (int i = 0; i < 4; ++i) {
    u16x4 vh, vl;
#pragma unroll
    for (int r = 0; r < 4; ++r) {
      u16 hh, ll; splitf(acc[i * 4 + r] * inv, hh, ll);
      vh[r] = hh; vl[r] = ll;
    }
    *(u16x4*)&oh[o + i * 4] = vh;
    *(u16x4*)&ol[o + i * 4] = vl;
  }
}

// ---------------------------------------------------------------------------
extern "C" void kernel_launch(void* const* d_in, const int* in_sizes, int n_in,
                              void* d_out, int out_size, void* d_ws, size_t ws_size,
                              hipStream_t stream) {
  const float* x     = (const float*)d_in[0];
  const float* w1    = (const float*)d_in[1];
  const float* b1    = (const float*)d_in[2];
  const float* w2    = (const float*)d_in[3];
  const float* b2    = (const float*)d_in[4];
  const float* w3    = (const float*)d_in[5];
  const float* b3    = (const float*)d_in[6];
  const float* w_out = (const float*)d_in[7];
  float* out = (float*)d_out;

  // ---- workspace layout (byte offsets) ----
  char* ws = (char*)d_ws;
  u16* XPH = (u16*)(ws + 0);                    //  7,102,464 B (16*1156*192*2)
  u16* XPL = (u16*)(ws + 7102464);
  u16* W1H = (u16*)(ws + 14204928);             //  2,654,208 B
  u16* W1L = (u16*)(ws + 16859136);
  u16* W2H = (u16*)(ws + 19513344);             //  1,179,648 B
  u16* W2L = (u16*)(ws + 20692992);
  u16* W3H = (u16*)(ws + 21872640);             //    884,736 B
  u16* W3L = (u16*)(ws + 22757376);
  u16* WOH = (u16*)(ws + 23642112);             //     73,728 B
  u16* WOL = (u16*)(ws + 23715840);
  // Region A @23,789,568 (50,331,648 B): a1 hi/lo -> a3 f32 -> o hi/lo
  u16*   A1H = (u16*)(ws + 23789568);
  u16*   A1L = (u16*)(ws + 48955392);
  float* A3  = (float*)(ws + 23789568);         // 37,748,736 B (a1 dead)
  u16*   OH  = (u16*)(ws + 23789568);           // after gather, a3 dead
  u16*   OL  = (u16*)(ws + 36372480);
  // Region B @74,121,216 (50,331,648 B): a2 hi/lo -> q,k,v f32
  u16*   A2H = (u16*)(ws + 74121216);
  u16*   A2L = (u16*)(ws + 99287040);
  float* Qb  = (float*)(ws + 74121216);         // 12,582,912 B each (a2 dead)
  float* Kb  = (float*)(ws + 86704128);
  float* Vb  = (float*)(ws + 99287040);
  // total: 124,452,864 B

  // ---- pack inputs to bf16 hi/lo ----
  pack_x_kernel<<<dim3(1734), 256, 0, stream>>>(x, XPH, XPL);
  pack_w1_kernel<<<dim3(576), 256, 0, stream>>>(w1, W1H, W1L);
  pack_gen_kernel<<<dim3(288), 256, 0, stream>>>(w2, W2H, W2L, 73728);
  pack_gen_kernel<<<dim3(216), 256, 0, stream>>>(w3, W3H, W3L, 55296);
  pack_gen_kernel<<<dim3(18), 256, 0, stream>>>(w_out, WOH, WOL, 4608);

  // ---- main pipeline ----
  conv_mfma_kernel<<<dim3(16, 6, 16), 256, 0, stream>>>(XPH, XPL, W1H, W1L, b1, A1H, A1L);
  gemm_mfma_kernel<0, 128><<<dim3(16, 6, 16), 256, 0, stream>>>(
      W2H, W2L, b2, A1H, A1L, A2H, A2L, HID_, HID_);
  gemm_mfma_kernel<1, 64><<<dim3(16, 9, 16), 256, 0, stream>>>(
      W3H, W3L, b3, A2H, A2L, A3, nullptr, C3_, HID_);
  qkv_gather_kernel<<<dim3(12288), 256, 0, stream>>>(A3, x, Qb, Kb, Vb);
  attn_kernel<<<dim3(4, 12, 16), 256, 0, stream>>>(Qb, Kb, Vb, OH, OL);
  gemm_mfma_kernel<2, 64><<<dim3(16, 3, 16), 256, 0, stream>>>(
      WOH, WOL, nullptr, OH, OL, out, nullptr, C_, C_);
}

// Round 4
// 535.215 us; speedup vs baseline: 2.8517x; 1.3110x over previous
//
#include <hip/hip_runtime.h>
#include <hip/hip_bf16.h>
#include <math.h>

// Problem constants
#define B_   16
#define P_   32
#define N_   1024
#define C_   192
#define H_   12
#define HD_  16
#define HID_ 768
#define C3_  576
#define SCALE_ 0.25f

using u16 = unsigned short;
typedef __bf16 bf16x8 __attribute__((ext_vector_type(8)));
typedef float f32x4 __attribute__((ext_vector_type(4)));
typedef u16 u16x8 __attribute__((ext_vector_type(8)));
typedef u16 u16x4 __attribute__((ext_vector_type(4)));

#define MFMA16(a, b, c) __builtin_amdgcn_mfma_f32_16x16x32_bf16((a), (b), (c), 0, 0, 0)

__device__ __forceinline__ int swz(int r) { return (r + (r >> 2)) & 3; }

__device__ __forceinline__ void splitf(float v, u16& h, u16& l) {
  union { __hip_bfloat16 b; u16 u; } c1, c2;
  c1.b = __float2bfloat16(v);
  float hv = __bfloat162float(c1.b);
  c2.b = __float2bfloat16(v - hv);
  h = c1.u; l = c2.u;
}

__device__ __forceinline__ u16 bfbits(float v) {
  union { __hip_bfloat16 b; u16 u; } c; c.b = __float2bfloat16(v); return c.u;
}

// LDS fragment read: tile stored as [row][32 k] u16, 64B rows, chunk-XOR swizzle.
__device__ __forceinline__ bf16x8 ldfrag(const u16* base, int row, int g) {
  return __builtin_bit_cast(bf16x8,
      *(const u16x8*)(base + row * 32 + ((g ^ swz(row)) << 3)));
}

// ---------------------------------------------------------------------------
// Pack x -> zero-padded 34x34 image, [b][pad_pixel][192ch] bf16 hi/lo.
__global__ __launch_bounds__(256) void pack_x_kernel(const float* __restrict__ x,
                                                     u16* __restrict__ xph,
                                                     u16* __restrict__ xpl) {
  int tid = blockIdx.x * 256 + threadIdx.x;   // 16*1156*24 = 443904 total
  int b = tid / 27744;
  int r = tid - b * 27744;
  int pp = r / 24;
  int cg = (r - pp * 24) * 8;
  int pr = pp / 34, pc = pp - pr * 34;
  float v[8] = {0.f, 0.f, 0.f, 0.f, 0.f, 0.f, 0.f, 0.f};
  if (pr >= 1 && pr <= 32 && pc >= 1 && pc <= 32) {
    const float* src = x + ((size_t)b * N_ + (pr - 1) * 32 + (pc - 1)) * C_ + cg;
    float4 v0 = *(const float4*)src;
    float4 v1 = *(const float4*)(src + 4);
    v[0] = v0.x; v[1] = v0.y; v[2] = v0.z; v[3] = v0.w;
    v[4] = v1.x; v[5] = v1.y; v[6] = v1.z; v[7] = v1.w;
  }
  u16x8 vh, vl;
#pragma unroll
  for (int i = 0; i < 8; ++i) { u16 h, l; splitf(v[i], h, l); vh[i] = h; vl[i] = l; }
  size_t o = ((size_t)b * 1156 + pp) * C_ + cg;
  *(u16x8*)&xph[o] = vh;
  *(u16x8*)&xpl[o] = vl;
}

// Pack w1 [768][192][3][3] -> [tap][768][192] hi/lo
__global__ __launch_bounds__(256) void pack_w1_kernel(const float* __restrict__ w1,
                                                      u16* __restrict__ w1h,
                                                      u16* __restrict__ w1l) {
  int tid = blockIdx.x * 256 + threadIdx.x;   // 147456
  int oc = tid / C_, ic = tid - oc * C_;
  const float* src = w1 + ((size_t)oc * C_ + ic) * 9;
#pragma unroll
  for (int t9 = 0; t9 < 9; ++t9) {
    u16 h, l; splitf(src[t9], h, l);
    size_t o = (size_t)t9 * (HID_ * C_) + oc * C_ + ic;
    w1h[o] = h; w1l[o] = l;
  }
}

// Generic elementwise pack
__global__ __launch_bounds__(256) void pack_gen_kernel(const float* __restrict__ src,
                                                       u16* __restrict__ dh,
                                                       u16* __restrict__ dl, int n8) {
  int tid = blockIdx.x * 256 + threadIdx.x;
  if (tid >= n8) return;
  const float* s = src + (size_t)tid * 8;
  float4 v0 = *(const float4*)s;
  float4 v1 = *(const float4*)(s + 4);
  float v[8] = {v0.x, v0.y, v0.z, v0.w, v1.x, v1.y, v1.z, v1.w};
  u16x8 vh, vl;
#pragma unroll
  for (int i = 0; i < 8; ++i) { u16 h, l; splitf(v[i], h, l); vh[i] = h; vl[i] = l; }
  *(u16x8*)&dh[(size_t)tid * 8] = vh;
  *(u16x8*)&dl[(size_t)tid * 8] = vl;
}

// ---------------------------------------------------------------------------
// conv3x3 as implicit GEMM via MFMA. Block: 128oc x 64px, 4 waves (2m x 2n).
__global__ __launch_bounds__(256) void conv_mfma_kernel(
    const u16* __restrict__ xph, const u16* __restrict__ xpl,
    const u16* __restrict__ w1h, const u16* __restrict__ w1l,
    const float* __restrict__ b1, u16* __restrict__ a1h, u16* __restrict__ a1l) {
  __shared__ u16 sA[2][128 * 32];
  __shared__ u16 sB[2][64 * 32];
  int t = threadIdx.x;
  int n0 = blockIdx.x * 64, oc0 = blockIdx.y * 128, b = blockIdx.z;
  int wid = t >> 6, lane = t & 63;
  int wm = wid >> 1, wn = wid & 1;
  int g = lane >> 4, lr = lane & 15;
  f32x4 acc[4][2] = {};

  for (int tap = 0; tap < 9; ++tap) {
    int dy = tap / 3, dx = tap - dy * 3;
    const u16* wth = w1h + (size_t)tap * (HID_ * C_);
    const u16* wtl = w1l + (size_t)tap * (HID_ * C_);
    for (int ks = 0; ks < 6; ++ks) {
      int kk = ks * 32;
      __syncthreads();
#pragma unroll
      for (int i = 0; i < 2; ++i) {
        int c = t + i * 256;
        int r = c >> 2, p = c & 3;
        size_t gidx = (size_t)(oc0 + r) * C_ + kk + p * 8;
        int lidx = r * 32 + ((p ^ swz(r)) << 3);
        *(u16x8*)&sA[0][lidx] = *(const u16x8*)&wth[gidx];
        *(u16x8*)&sA[1][lidx] = *(const u16x8*)&wtl[gidx];
      }
      {
        int c = t;
        int r = c >> 2, p = c & 3;
        int pix = n0 + r;
        int py = pix >> 5, px = pix & 31;
        int pad = (py + dy) * 34 + (px + dx);
        size_t gidx = ((size_t)b * 1156 + pad) * C_ + kk + p * 8;
        int lidx = r * 32 + ((p ^ swz(r)) << 3);
        *(u16x8*)&sB[0][lidx] = *(const u16x8*)&xph[gidx];
        *(u16x8*)&sB[1][lidx] = *(const u16x8*)&xpl[gidx];
      }
      __syncthreads();
      bf16x8 ah[4], al[4], bh[2], bl[2];
#pragma unroll
      for (int mf = 0; mf < 4; ++mf) {
        int row = wm * 64 + mf * 16 + lr;
        ah[mf] = ldfrag(&sA[0][0], row, g);
        al[mf] = ldfrag(&sA[1][0], row, g);
      }
#pragma unroll
      for (int nf = 0; nf < 2; ++nf) {
        int row = wn * 32 + nf * 16 + lr;
        bh[nf] = ldfrag(&sB[0][0], row, g);
        bl[nf] = ldfrag(&sB[1][0], row, g);
      }
#pragma unroll
      for (int mf = 0; mf < 4; ++mf)
#pragma unroll
        for (int nf = 0; nf < 2; ++nf) {
          acc[mf][nf] = MFMA16(ah[mf], bh[nf], acc[mf][nf]);
          acc[mf][nf] = MFMA16(al[mf], bh[nf], acc[mf][nf]);
          acc[mf][nf] = MFMA16(ah[mf], bl[nf], acc[mf][nf]);
        }
    }
  }
#pragma unroll
  for (int mf = 0; mf < 4; ++mf)
#pragma unroll
    for (int nf = 0; nf < 2; ++nf) {
      int pix = n0 + wn * 32 + nf * 16 + lr;
      int oc = oc0 + wm * 64 + mf * 16 + g * 4;
      size_t oidx = ((size_t)b * N_ + pix) * HID_ + oc;
      u16x4 vh, vl;
#pragma unroll
      for (int r = 0; r < 4; ++r) {
        float v = acc[mf][nf][r] + b1[oc + r];
        v = v > 0.f ? v : 0.f;
        u16 h, l; splitf(v, h, l);
        vh[r] = h; vl[r] = l;
      }
      *(u16x4*)&a1h[oidx] = vh;
      *(u16x4*)&a1l[oidx] = vl;
    }
}

// ---------------------------------------------------------------------------
// Generic MFMA GEMM over [pixel][IC] activations.
// ACT: 0 relu->bf16 hi/lo, 1 sigmoid->f32, 2 none->f32.
template <int ACT, int MT>
__global__ __launch_bounds__(256) void gemm_mfma_kernel(
    const u16* __restrict__ Wh, const u16* __restrict__ Wl,
    const float* __restrict__ bias,
    const u16* __restrict__ inh, const u16* __restrict__ inl,
    void* __restrict__ out0, void* __restrict__ out1, int OC, int IC) {
  constexpr int MF = MT / 32;
  __shared__ u16 sA[2][MT * 32];
  __shared__ u16 sB[2][64 * 32];
  int t = threadIdx.x;
  int n0 = blockIdx.x * 64, oc0 = blockIdx.y * MT, b = blockIdx.z;
  int wid = t >> 6, lane = t & 63;
  int wm = wid >> 1, wn = wid & 1;
  int g = lane >> 4, lr = lane & 15;
  const u16* inbh = inh + (size_t)b * N_ * IC;
  const u16* inbl = inl + (size_t)b * N_ * IC;
  f32x4 acc[MF][2] = {};

  for (int ks = 0; ks < IC / 32; ++ks) {
    int kk = ks * 32;
    __syncthreads();
    for (int c = t; c < MT * 4; c += 256) {
      int r = c >> 2, p = c & 3;
      size_t gidx = (size_t)(oc0 + r) * IC + kk + p * 8;
      int lidx = r * 32 + ((p ^ swz(r)) << 3);
      *(u16x8*)&sA[0][lidx] = *(const u16x8*)&Wh[gidx];
      *(u16x8*)&sA[1][lidx] = *(const u16x8*)&Wl[gidx];
    }
    {
      int c = t;
      int r = c >> 2, p = c & 3;
      size_t gidx = (size_t)(n0 + r) * IC + kk + p * 8;
      int lidx = r * 32 + ((p ^ swz(r)) << 3);
      *(u16x8*)&sB[0][lidx] = *(const u16x8*)&inbh[gidx];
      *(u16x8*)&sB[1][lidx] = *(const u16x8*)&inbl[gidx];
    }
    __syncthreads();
    bf16x8 ah[MF], al[MF], bh[2], bl[2];
#pragma unroll
    for (int mf = 0; mf < MF; ++mf) {
      int row = wm * (MT / 2) + mf * 16 + lr;
      ah[mf] = ldfrag(&sA[0][0], row, g);
      al[mf] = ldfrag(&sA[1][0], row, g);
    }
#pragma unroll
    for (int nf = 0; nf < 2; ++nf) {
      int row = wn * 32 + nf * 16 + lr;
      bh[nf] = ldfrag(&sB[0][0], row, g);
      bl[nf] = ldfrag(&sB[1][0], row, g);
    }
#pragma unroll
    for (int mf = 0; mf < MF; ++mf)
#pragma unroll
      for (int nf = 0; nf < 2; ++nf) {
        acc[mf][nf] = MFMA16(ah[mf], bh[nf], acc[mf][nf]);
        acc[mf][nf] = MFMA16(al[mf], bh[nf], acc[mf][nf]);
        acc[mf][nf] = MFMA16(ah[mf], bl[nf], acc[mf][nf]);
      }
  }
#pragma unroll
  for (int mf = 0; mf < MF; ++mf)
#pragma unroll
    for (int nf = 0; nf < 2; ++nf) {
      int pix = n0 + wn * 32 + nf * 16 + lr;
      int oc = oc0 + wm * (MT / 2) + mf * 16 + g * 4;
      size_t oidx = ((size_t)b * N_ + pix) * OC + oc;
      if constexpr (ACT == 0) {
        u16x4 vh, vl;
#pragma unroll
        for (int r = 0; r < 4; ++r) {
          float v = acc[mf][nf][r] + bias[oc + r];
          v = v > 0.f ? v : 0.f;
          u16 h, l; splitf(v, h, l);
          vh[r] = h; vl[r] = l;
        }
        *(u16x4*)&((u16*)out0)[oidx] = vh;
        *(u16x4*)&((u16*)out1)[oidx] = vl;
      } else if constexpr (ACT == 1) {
        float4 res;
        float r0 = acc[mf][nf][0] + bias[oc + 0];
        float r1 = acc[mf][nf][1] + bias[oc + 1];
        float r2 = acc[mf][nf][2] + bias[oc + 2];
        float r3 = acc[mf][nf][3] + bias[oc + 3];
        res.x = 1.f / (1.f + __expf(-r0)); res.y = 1.f / (1.f + __expf(-r1));
        res.z = 1.f / (1.f + __expf(-r2)); res.w = 1.f / (1.f + __expf(-r3));
        *(float4*)&((float*)out0)[oidx] = res;
      } else {
        float4 res;
        res.x = acc[mf][nf][0]; res.y = acc[mf][nf][1];
        res.z = acc[mf][nf][2]; res.w = acc[mf][nf][3];
        *(float4*)&((float*)out0)[oidx] = res;
      }
    }
}

// ---------------------------------------------------------------------------
// qkv gather: a3 [b][pixel][576] f32 -> QH/QL/KH/KL (bf16 hi/lo) + VB (bf16)
// in [b,h,n,16] u16 layout. Same flat-index scramble as reference.
__global__ __launch_bounds__(256) void qkv_gather_kernel(const float* __restrict__ a3,
                                                         const float* __restrict__ x,
                                                         u16* __restrict__ qh,
                                                         u16* __restrict__ ql,
                                                         u16* __restrict__ kh,
                                                         u16* __restrict__ kl,
                                                         u16* __restrict__ vb) {
  int idx = blockIdx.x * 256 + threadIdx.x;
  int b = idx / 196608;
  int gg = idx - b * 196608;
  int m = gg & 1023, cc = gg >> 10;
  int j = m * 192 + cc;
  float y = x[((size_t)b * N_ + (j & 1023)) * C_ + (j >> 10)];
  int n2 = gg / 192;
  int hd = gg - n2 * 192;
  size_t out_idx = (((size_t)b * H_ + (hd >> 4)) * N_ + n2) * HD_ + (hd & 15);
  const float* a3b = a3 + (size_t)b * (C3_ * N_);
  int jk = j + 196608, jv = j + 393216;
  int nq = j / 576,  chq = j - nq * 576;
  int nk = jk / 576, chk = jk - nk * 576;
  int nv = jv / 576, chv = jv - nv * 576;
  float aq = a3b[(size_t)nq * C3_ + chq];
  float ak = a3b[(size_t)nk * C3_ + chk];
  float av = a3b[(size_t)nv * C3_ + chv];
  u16 hh, ll;
  splitf(aq * y * SCALE_, hh, ll); qh[out_idx] = hh; ql[out_idx] = ll;
  splitf(ak * y, hh, ll);          kh[out_idx] = hh; kl[out_idx] = ll;
  vb[out_idx] = bfbits(av * y);
}

// ---------------------------------------------------------------------------
// MFMA flash attention. grid (16 qtiles, 12 h, 16 b), 4 waves x 16 q-rows.
// Swapped QK^T (S^T[key,q], d padded 16->32) and swapped PV (O^T[d,q]).
// Q/K hi/lo bf16 (3-mfma), P/V single bf16.
__global__ __launch_bounds__(256) void attn_mfma_kernel(
    const u16* __restrict__ QH, const u16* __restrict__ QL,
    const u16* __restrict__ KH, const u16* __restrict__ KL,
    const u16* __restrict__ VB, u16* __restrict__ oh, u16* __restrict__ ol) {
  __shared__ u16 sKH[64 * 32];   // [key][32 d-padded] swizzled, hi
  __shared__ u16 sKL[64 * 32];   // lo
  __shared__ u16 sVT[16 * 64];   // [d][64 keys], 16B-chunk XOR swizzle
  __shared__ u16 sP[4][16 * 64]; // per-wave P^T bounce [q][64 keys]
  int t = threadIdx.x;
  int qt = blockIdx.x, h = blockIdx.y, b = blockIdx.z;
  int wid = t >> 6, lane = t & 63;
  int lr = lane & 15, g = lane >> 4;
  size_t base = ((size_t)(b * H_ + h)) * (N_ * HD_);
  int qrow = qt * 64 + wid * 16 + lr;

  // zero the d=16..31 pad chunks of sKH/sKL once (swizzle-consistent positions)
  {
    int plane = t >> 7, r = (t >> 1) & 63, gg = 2 + (t & 1);
    u16* dst = (plane ? sKL : sKH) + r * 32 + ((gg ^ swz(r)) << 3);
    u16x8 z = {};
    *(u16x8*)dst = z;
  }

  // Q fragments (held in registers): lane lr = q-col, g = d-slice (g>=2 zero)
  bf16x8 qfh = {}, qfl = {};
  if (g < 2) {
    size_t qi = base + (size_t)qrow * HD_ + g * 8;
    qfh = __builtin_bit_cast(bf16x8, *(const u16x8*)&QH[qi]);
    qfl = __builtin_bit_cast(bf16x8, *(const u16x8*)&QL[qi]);
  }

  f32x4 acc = {};
  float mrun = -1e30f, lrun = 0.f;
  u16* pw = &sP[wid][0];

  for (int ch = 0; ch < 16; ++ch) {
    int key0 = ch * 64;
    __syncthreads();
    // ---- stage K chunk (hi: t<128, lo: t>=128), [64 keys][16 real d] ----
    {
      int r = (t & 127) >> 1, gg = t & 1;
      const u16* src = (t < 128 ? KH : KL) + base + (size_t)(key0 + r) * HD_ + gg * 8;
      u16* dst = (t < 128 ? sKH : sKL) + r * 32 + ((gg ^ swz(r)) << 3);
      *(u16x8*)dst = *(const u16x8*)src;
    }
    // ---- stage V^T: [d][64 keys] via u16 scatter ----
    {
      int key = t >> 2, d0 = (t & 3) * 4;
      u16x4 vv = *(const u16x4*)&VB[base + (size_t)(key0 + key) * HD_ + d0];
#pragma unroll
      for (int i = 0; i < 4; ++i) {
        int d = d0 + i;
        sVT[d * 64 + (((key >> 3) ^ (d & 7)) << 3) + (key & 7)] = vv[i];
      }
    }
    __syncthreads();

    // ---- QK^T: 4 key-subtiles, S^T[key,q], hi/lo 3-mfma ----
    f32x4 st[4];
#pragma unroll
    for (int t4 = 0; t4 < 4; ++t4) {
      bf16x8 kfh = ldfrag(sKH, t4 * 16 + lr, g);
      bf16x8 kfl = ldfrag(sKL, t4 * 16 + lr, g);
      f32x4 s = {};
      s = MFMA16(kfh, qfl, s);
      s = MFMA16(kfl, qfh, s);
      s = MFMA16(kfh, qfh, s);
      st[t4] = s;
    }

    // ---- online softmax: lane owns q=lr; keys split over 4 lanes (g) ----
    float cmax = -1e30f;
#pragma unroll
    for (int t4 = 0; t4 < 4; ++t4)
#pragma unroll
      for (int r = 0; r < 4; ++r) cmax = fmaxf(cmax, st[t4][r]);
    cmax = fmaxf(cmax, __shfl_xor(cmax, 16));
    cmax = fmaxf(cmax, __shfl_xor(cmax, 32));
    float mnew = fmaxf(mrun, cmax);
    float corr = __expf(mrun - mnew);
    float p[16];
    float psum = 0.f;
#pragma unroll
    for (int t4 = 0; t4 < 4; ++t4)
#pragma unroll
      for (int r = 0; r < 4; ++r) {
        float pv = __expf(st[t4][r] - mnew);
        p[t4 * 4 + r] = pv; psum += pv;
      }
    psum += __shfl_xor(psum, 16);
    psum += __shfl_xor(psum, 32);
    lrun = lrun * corr + psum;
    mrun = mnew;
#pragma unroll
    for (int r = 0; r < 4; ++r) acc[r] *= corr;

    // ---- pack P to bf16, bounce via per-wave LDS to re-group keys ----
#pragma unroll
    for (int t4 = 0; t4 < 4; ++t4) {
      unsigned w0 = (unsigned)bfbits(p[t4 * 4 + 0]) | ((unsigned)bfbits(p[t4 * 4 + 1]) << 16);
      unsigned w1 = (unsigned)bfbits(p[t4 * 4 + 2]) | ((unsigned)bfbits(p[t4 * 4 + 3]) << 16);
      int c = 2 * t4 + (g >> 1);
      int off = lr * 64 + ((c ^ (lr & 7)) << 3) + (g & 1) * 4;  // u16 units
      uint2 val; val.x = w0; val.y = w1;
      *(uint2*)&pw[off] = val;
    }
    // ---- PV: O^T += V^T-frag x P^T-frag, 2 key-halves ----
#pragma unroll
    for (int kk = 0; kk < 2; ++kk) {
      int off = lr * 64 + (((4 * kk + g) ^ (lr & 7)) << 3);
      bf16x8 pb = __builtin_bit_cast(bf16x8, *(const u16x8*)&pw[off]);
      bf16x8 va = __builtin_bit_cast(bf16x8, *(const u16x8*)&sVT[off]);
      acc = MFMA16(va, pb, acc);
    }
  }

  // ---- epilogue: lane owns q=lr, d = 4g + reg ----
  float inv = 1.0f / lrun;
  size_t o = ((size_t)b * N_ + qrow) * C_ + h * HD_ + 4 * g;
  u16x4 vh, vl;
#pragma unroll
  for (int r = 0; r < 4; ++r) {
    u16 hh, ll; splitf(acc[r] * inv, hh, ll);
    vh[r] = hh; vl[r] = ll;
  }
  *(u16x4*)&oh[o] = vh;
  *(u16x4*)&ol[o] = vl;
}

// ---------------------------------------------------------------------------
extern "C" void kernel_launch(void* const* d_in, const int* in_sizes, int n_in,
                              void* d_out, int out_size, void* d_ws, size_t ws_size,
                              hipStream_t stream) {
  const float* x     = (const float*)d_in[0];
  const float* w1    = (const float*)d_in[1];
  const float* b1    = (const float*)d_in[2];
  const float* w2    = (const float*)d_in[3];
  const float* b2    = (const float*)d_in[4];
  const float* w3    = (const float*)d_in[5];
  const float* b3    = (const float*)d_in[6];
  const float* w_out = (const float*)d_in[7];
  float* out = (float*)d_out;

  // ---- workspace layout (byte offsets) ----
  char* ws = (char*)d_ws;
  u16* XPH = (u16*)(ws + 0);                    //  7,102,464 B
  u16* XPL = (u16*)(ws + 7102464);
  u16* W1H = (u16*)(ws + 14204928);             //  2,654,208 B
  u16* W1L = (u16*)(ws + 16859136);
  u16* W2H = (u16*)(ws + 19513344);             //  1,179,648 B
  u16* W2L = (u16*)(ws + 20692992);
  u16* W3H = (u16*)(ws + 21872640);             //    884,736 B
  u16* W3L = (u16*)(ws + 22757376);
  u16* WOH = (u16*)(ws + 23642112);             //     73,728 B
  u16* WOL = (u16*)(ws + 23715840);
  // Region A @23,789,568: a1 hi/lo -> a3 f32 -> o hi/lo
  u16*   A1H = (u16*)(ws + 23789568);
  u16*   A1L = (u16*)(ws + 48955392);
  float* A3  = (float*)(ws + 23789568);         // a1 dead
  u16*   OH  = (u16*)(ws + 23789568);           // a3 dead after gather
  u16*   OL  = (u16*)(ws + 36372480);
  // Region B @74,121,216: a2 hi/lo -> QH/QL/KH/KL/VB u16 (6,291,456 B each)
  u16*   A2H = (u16*)(ws + 74121216);
  u16*   A2L = (u16*)(ws + 99287040);
  u16*   QHb = (u16*)(ws + 74121216);           // a2 dead
  u16*   QLb = (u16*)(ws + 80412672);
  u16*   KHb = (u16*)(ws + 86704128);
  u16*   KLb = (u16*)(ws + 92995584);
  u16*   VBb = (u16*)(ws + 99287040);
  // total: 124,452,864 B

  // ---- pack inputs to bf16 hi/lo ----
  pack_x_kernel<<<dim3(1734), 256, 0, stream>>>(x, XPH, XPL);
  pack_w1_kernel<<<dim3(576), 256, 0, stream>>>(w1, W1H, W1L);
  pack_gen_kernel<<<dim3(288), 256, 0, stream>>>(w2, W2H, W2L, 73728);
  pack_gen_kernel<<<dim3(216), 256, 0, stream>>>(w3, W3H, W3L, 55296);
  pack_gen_kernel<<<dim3(18), 256, 0, stream>>>(w_out, WOH, WOL, 4608);

  // ---- main pipeline ----
  conv_mfma_kernel<<<dim3(16, 6, 16), 256, 0, stream>>>(XPH, XPL, W1H, W1L, b1, A1H, A1L);
  gemm_mfma_kernel<0, 128><<<dim3(16, 6, 16), 256, 0, stream>>>(
      W2H, W2L, b2, A1H, A1L, A2H, A2L, HID_, HID_);
  gemm_mfma_kernel<1, 64><<<dim3(16, 9, 16), 256, 0, stream>>>(
      W3H, W3L, b3, A2H, A2L, A3, nullptr, C3_, HID_);
  qkv_gather_kernel<<<dim3(12288), 256, 0, stream>>>(A3, x, QHb, QLb, KHb, KLb, VBb);
  attn_mfma_kernel<<<dim3(16, 12, 16), 256, 0, stream>>>(QHb, QLb, KHb, KLb, VBb, OH, OL);
  gemm_mfma_kernel<2, 64><<<dim3(16, 3, 16), 256, 0, stream>>>(
      WOH, WOL, nullptr, OH, OL, out, nullptr, C_, C_);
}

// Round 6
// 498.119 us; speedup vs baseline: 3.0641x; 1.0745x over previous
//
#include <hip/hip_runtime.h>
#include <hip/hip_bf16.h>
#include <math.h>

// Problem constants
#define B_   16
#define P_   32
#define N_   1024
#define C_   192
#define H_   12
#define HD_  16
#define HID_ 768
#define C3_  576
#define SCALE_ 0.25f

using u16 = unsigned short;
typedef __bf16 bf16x8 __attribute__((ext_vector_type(8)));
typedef float f32x4 __attribute__((ext_vector_type(4)));
typedef u16 u16x8 __attribute__((ext_vector_type(8)));
typedef u16 u16x4 __attribute__((ext_vector_type(4)));

#define MFMA16(a, b, c) __builtin_amdgcn_mfma_f32_16x16x32_bf16((a), (b), (c), 0, 0, 0)

__device__ __forceinline__ int swz(int r) { return (r + (r >> 2)) & 3; }

__device__ __forceinline__ void splitf(float v, u16& h, u16& l) {
  union { __hip_bfloat16 b; u16 u; } c1, c2;
  c1.b = __float2bfloat16(v);
  float hv = __bfloat162float(c1.b);
  c2.b = __float2bfloat16(v - hv);
  h = c1.u; l = c2.u;
}

__device__ __forceinline__ u16 bfbits(float v) {
  union { __hip_bfloat16 b; u16 u; } c; c.b = __float2bfloat16(v); return c.u;
}

// LDS fragment read: tile stored as [row][32 k] u16, 64B rows, chunk-XOR swizzle.
__device__ __forceinline__ bf16x8 ldfrag(const u16* base, int row, int g) {
  return __builtin_bit_cast(bf16x8,
      *(const u16x8*)(base + row * 32 + ((g ^ swz(row)) << 3)));
}

// ---------------------------------------------------------------------------
// Pack x -> zero-padded 34x34 image, [b][pad_pixel][192ch] bf16 hi/lo.
__global__ __launch_bounds__(256) void pack_x_kernel(const float* __restrict__ x,
                                                     u16* __restrict__ xph,
                                                     u16* __restrict__ xpl) {
  int tid = blockIdx.x * 256 + threadIdx.x;   // 16*1156*24 = 443904 total
  int b = tid / 27744;
  int r = tid - b * 27744;
  int pp = r / 24;
  int cg = (r - pp * 24) * 8;
  int pr = pp / 34, pc = pp - pr * 34;
  float v[8] = {0.f, 0.f, 0.f, 0.f, 0.f, 0.f, 0.f, 0.f};
  if (pr >= 1 && pr <= 32 && pc >= 1 && pc <= 32) {
    const float* src = x + ((size_t)b * N_ + (pr - 1) * 32 + (pc - 1)) * C_ + cg;
    float4 v0 = *(const float4*)src;
    float4 v1 = *(const float4*)(src + 4);
    v[0] = v0.x; v[1] = v0.y; v[2] = v0.z; v[3] = v0.w;
    v[4] = v1.x; v[5] = v1.y; v[6] = v1.z; v[7] = v1.w;
  }
  u16x8 vh, vl;
#pragma unroll
  for (int i = 0; i < 8; ++i) { u16 h, l; splitf(v[i], h, l); vh[i] = h; vl[i] = l; }
  size_t o = ((size_t)b * 1156 + pp) * C_ + cg;
  *(u16x8*)&xph[o] = vh;
  *(u16x8*)&xpl[o] = vl;
}

// Pack w1 [768][192][3][3] -> [tap][768][192] hi/lo
__global__ __launch_bounds__(256) void pack_w1_kernel(const float* __restrict__ w1,
                                                      u16* __restrict__ w1h,
                                                      u16* __restrict__ w1l) {
  int tid = blockIdx.x * 256 + threadIdx.x;   // 147456
  int oc = tid / C_, ic = tid - oc * C_;
  const float* src = w1 + ((size_t)oc * C_ + ic) * 9;
#pragma unroll
  for (int t9 = 0; t9 < 9; ++t9) {
    u16 h, l; splitf(src[t9], h, l);
    size_t o = (size_t)t9 * (HID_ * C_) + oc * C_ + ic;
    w1h[o] = h; w1l[o] = l;
  }
}

// Generic elementwise pack
__global__ __launch_bounds__(256) void pack_gen_kernel(const float* __restrict__ src,
                                                       u16* __restrict__ dh,
                                                       u16* __restrict__ dl, int n8) {
  int tid = blockIdx.x * 256 + threadIdx.x;
  if (tid >= n8) return;
  const float* s = src + (size_t)tid * 8;
  float4 v0 = *(const float4*)s;
  float4 v1 = *(const float4*)(s + 4);
  float v[8] = {v0.x, v0.y, v0.z, v0.w, v1.x, v1.y, v1.z, v1.w};
  u16x8 vh, vl;
#pragma unroll
  for (int i = 0; i < 8; ++i) { u16 h, l; splitf(v[i], h, l); vh[i] = h; vl[i] = l; }
  *(u16x8*)&dh[(size_t)tid * 8] = vh;
  *(u16x8*)&dl[(size_t)tid * 8] = vl;
}

// ---------------------------------------------------------------------------
// conv3x3 as implicit GEMM via MFMA. Block: 128oc x 128px, 4 waves (2m x 2n),
// each wave 64oc x 64px (4x4 subtiles). grid (8, 6, 16).
__global__ __launch_bounds__(256) void conv_mfma_kernel(
    const u16* __restrict__ xph, const u16* __restrict__ xpl,
    const u16* __restrict__ w1h, const u16* __restrict__ w1l,
    const float* __restrict__ b1, u16* __restrict__ a1h, u16* __restrict__ a1l) {
  __shared__ u16 sA[2][128 * 32];
  __shared__ u16 sB[2][128 * 32];
  int t = threadIdx.x;
  int n0 = blockIdx.x * 128, oc0 = blockIdx.y * 128, b = blockIdx.z;
  int wid = t >> 6, lane = t & 63;
  int wm = wid >> 1, wn = wid & 1;
  int g = lane >> 4, lr = lane & 15;
  f32x4 acc[4][4] = {};

  for (int tap = 0; tap < 9; ++tap) {
    int dy = tap / 3, dx = tap - dy * 3;
    const u16* wth = w1h + (size_t)tap * (HID_ * C_);
    const u16* wtl = w1l + (size_t)tap * (HID_ * C_);
    for (int ks = 0; ks < 6; ++ks) {
      int kk = ks * 32;
      __syncthreads();
      // stage A (weights): 128 rows x 32k, hi+lo
#pragma unroll
      for (int i = 0; i < 2; ++i) {
        int c = t + i * 256;
        int r = c >> 2, p = c & 3;
        size_t gidx = (size_t)(oc0 + r) * C_ + kk + p * 8;
        int lidx = r * 32 + ((p ^ swz(r)) << 3);
        *(u16x8*)&sA[0][lidx] = *(const u16x8*)&wth[gidx];
        *(u16x8*)&sA[1][lidx] = *(const u16x8*)&wtl[gidx];
      }
      // stage B (shifted pixels): 128 rows x 32k, hi+lo
#pragma unroll
      for (int i = 0; i < 2; ++i) {
        int c = t + i * 256;
        int r = c >> 2, p = c & 3;
        int pix = n0 + r;
        int py = pix >> 5, px = pix & 31;
        int pad = (py + dy) * 34 + (px + dx);
        size_t gidx = ((size_t)b * 1156 + pad) * C_ + kk + p * 8;
        int lidx = r * 32 + ((p ^ swz(r)) << 3);
        *(u16x8*)&sB[0][lidx] = *(const u16x8*)&xph[gidx];
        *(u16x8*)&sB[1][lidx] = *(const u16x8*)&xpl[gidx];
      }
      __syncthreads();
      bf16x8 ah[4], al[4], bh[4], bl[4];
#pragma unroll
      for (int mf = 0; mf < 4; ++mf) {
        int row = wm * 64 + mf * 16 + lr;
        ah[mf] = ldfrag(&sA[0][0], row, g);
        al[mf] = ldfrag(&sA[1][0], row, g);
      }
#pragma unroll
      for (int nf = 0; nf < 4; ++nf) {
        int row = wn * 64 + nf * 16 + lr;
        bh[nf] = ldfrag(&sB[0][0], row, g);
        bl[nf] = ldfrag(&sB[1][0], row, g);
      }
#pragma unroll
      for (int mf = 0; mf < 4; ++mf)
#pragma unroll
        for (int nf = 0; nf < 4; ++nf) {
          acc[mf][nf] = MFMA16(ah[mf], bh[nf], acc[mf][nf]);
          acc[mf][nf] = MFMA16(al[mf], bh[nf], acc[mf][nf]);
          acc[mf][nf] = MFMA16(ah[mf], bl[nf], acc[mf][nf]);
        }
    }
  }
#pragma unroll
  for (int mf = 0; mf < 4; ++mf)
#pragma unroll
    for (int nf = 0; nf < 4; ++nf) {
      int pix = n0 + wn * 64 + nf * 16 + lr;
      int oc = oc0 + wm * 64 + mf * 16 + g * 4;
      size_t oidx = ((size_t)b * N_ + pix) * HID_ + oc;
      u16x4 vh, vl;
#pragma unroll
      for (int r = 0; r < 4; ++r) {
        float v = acc[mf][nf][r] + b1[oc + r];
        v = v > 0.f ? v : 0.f;
        u16 h, l; splitf(v, h, l);
        vh[r] = h; vl[r] = l;
      }
      *(u16x4*)&a1h[oidx] = vh;
      *(u16x4*)&a1l[oidx] = vl;
    }
}

// ---------------------------------------------------------------------------
// Generic MFMA GEMM over [pixel][IC] activations. Block tile MT x 128px,
// 4 waves (2m x 2n), wave tile (MT/2) x 64. grid (8, OC/MT, 16).
// ACT: 0 relu->bf16 hi/lo, 1 sigmoid->f32, 2 none->f32.
template <int ACT, int MT>
__global__ __launch_bounds__(256) void gemm_mfma_kernel(
    const u16* __restrict__ Wh, const u16* __restrict__ Wl,
    const float* __restrict__ bias,
    const u16* __restrict__ inh, const u16* __restrict__ inl,
    void* __restrict__ out0, void* __restrict__ out1, int OC, int IC) {
  constexpr int MF = MT / 32;
  __shared__ u16 sA[2][MT * 32];
  __shared__ u16 sB[2][128 * 32];
  int t = threadIdx.x;
  int n0 = blockIdx.x * 128, oc0 = blockIdx.y * MT, b = blockIdx.z;
  int wid = t >> 6, lane = t & 63;
  int wm = wid >> 1, wn = wid & 1;
  int g = lane >> 4, lr = lane & 15;
  const u16* inbh = inh + (size_t)b * N_ * IC;
  const u16* inbl = inl + (size_t)b * N_ * IC;
  f32x4 acc[MF][4] = {};

  for (int ks = 0; ks < IC / 32; ++ks) {
    int kk = ks * 32;
    __syncthreads();
    for (int c = t; c < MT * 4; c += 256) {
      int r = c >> 2, p = c & 3;
      size_t gidx = (size_t)(oc0 + r) * IC + kk + p * 8;
      int lidx = r * 32 + ((p ^ swz(r)) << 3);
      *(u16x8*)&sA[0][lidx] = *(const u16x8*)&Wh[gidx];
      *(u16x8*)&sA[1][lidx] = *(const u16x8*)&Wl[gidx];
    }
#pragma unroll
    for (int i = 0; i < 2; ++i) {
      int c = t + i * 256;
      int r = c >> 2, p = c & 3;
      size_t gidx = (size_t)(n0 + r) * IC + kk + p * 8;
      int lidx = r * 32 + ((p ^ swz(r)) << 3);
      *(u16x8*)&sB[0][lidx] = *(const u16x8*)&inbh[gidx];
      *(u16x8*)&sB[1][lidx] = *(const u16x8*)&inbl[gidx];
    }
    __syncthreads();
    bf16x8 ah[MF], al[MF], bh[4], bl[4];
#pragma unroll
    for (int mf = 0; mf < MF; ++mf) {
      int row = wm * (MT / 2) + mf * 16 + lr;
      ah[mf] = ldfrag(&sA[0][0], row, g);
      al[mf] = ldfrag(&sA[1][0], row, g);
    }
#pragma unroll
    for (int nf = 0; nf < 4; ++nf) {
      int row = wn * 64 + nf * 16 + lr;
      bh[nf] = ldfrag(&sB[0][0], row, g);
      bl[nf] = ldfrag(&sB[1][0], row, g);
    }
#pragma unroll
    for (int mf = 0; mf < MF; ++mf)
#pragma unroll
      for (int nf = 0; nf < 4; ++nf) {
        acc[mf][nf] = MFMA16(ah[mf], bh[nf], acc[mf][nf]);
        acc[mf][nf] = MFMA16(al[mf], bh[nf], acc[mf][nf]);
        acc[mf][nf] = MFMA16(ah[mf], bl[nf], acc[mf][nf]);
      }
  }
#pragma unroll
  for (int mf = 0; mf < MF; ++mf)
#pragma unroll
    for (int nf = 0; nf < 4; ++nf) {
      int pix = n0 + wn * 64 + nf * 16 + lr;
      int oc = oc0 + wm * (MT / 2) + mf * 16 + g * 4;
      size_t oidx = ((size_t)b * N_ + pix) * OC + oc;
      if constexpr (ACT == 0) {
        u16x4 vh, vl;
#pragma unroll
        for (int r = 0; r < 4; ++r) {
          float v = acc[mf][nf][r] + bias[oc + r];
          v = v > 0.f ? v : 0.f;
          u16 h, l; splitf(v, h, l);
          vh[r] = h; vl[r] = l;
        }
        *(u16x4*)&((u16*)out0)[oidx] = vh;
        *(u16x4*)&((u16*)out1)[oidx] = vl;
      } else if constexpr (ACT == 1) {
        float4 res;
        float r0 = acc[mf][nf][0] + bias[oc + 0];
        float r1 = acc[mf][nf][1] + bias[oc + 1];
        float r2 = acc[mf][nf][2] + bias[oc + 2];
        float r3 = acc[mf][nf][3] + bias[oc + 3];
        res.x = 1.f / (1.f + __expf(-r0)); res.y = 1.f / (1.f + __expf(-r1));
        res.z = 1.f / (1.f + __expf(-r2)); res.w = 1.f / (1.f + __expf(-r3));
        *(float4*)&((float*)out0)[oidx] = res;
      } else {
        float4 res;
        res.x = acc[mf][nf][0]; res.y = acc[mf][nf][1];
        res.z = acc[mf][nf][2]; res.w = acc[mf][nf][3];
        *(float4*)&((float*)out0)[oidx] = res;
      }
    }
}

// ---------------------------------------------------------------------------
// qkv gather: a3 [b][pixel][576] f32 -> QH/QL/KH/KL (bf16 hi/lo) + VB (bf16)
// in [b,h,n,16] u16 layout. Same flat-index scramble as reference.
__global__ __launch_bounds__(256) void qkv_gather_kernel(const float* __restrict__ a3,
                                                         const float* __restrict__ x,
                                                         u16* __restrict__ qh,
                                                         u16* __restrict__ ql,
                                                         u16* __restrict__ kh,
                                                         u16* __restrict__ kl,
                                                         u16* __restrict__ vb) {
  int idx = blockIdx.x * 256 + threadIdx.x;
  int b = idx / 196608;
  int gg = idx - b * 196608;
  int m = gg & 1023, cc = gg >> 10;
  int j = m * 192 + cc;
  float y = x[((size_t)b * N_ + (j & 1023)) * C_ + (j >> 10)];
  int n2 = gg / 192;
  int hd = gg - n2 * 192;
  size_t out_idx = (((size_t)b * H_ + (hd >> 4)) * N_ + n2) * HD_ + (hd & 15);
  const float* a3b = a3 + (size_t)b * (C3_ * N_);
  int jk = j + 196608, jv = j + 393216;
  int nq = j / 576,  chq = j - nq * 576;
  int nk = jk / 576, chk = jk - nk * 576;
  int nv = jv / 576, chv = jv - nv * 576;
  float aq = a3b[(size_t)nq * C3_ + chq];
  float ak = a3b[(size_t)nk * C3_ + chk];
  float av = a3b[(size_t)nv * C3_ + chv];
  u16 hh, ll;
  splitf(aq * y * SCALE_, hh, ll); qh[out_idx] = hh; ql[out_idx] = ll;
  splitf(ak * y, hh, ll);          kh[out_idx] = hh; kl[out_idx] = ll;
  vb[out_idx] = bfbits(av * y);
}

// ---------------------------------------------------------------------------
// MFMA flash attention. grid (16 qtiles, 12 h, 16 b), 4 waves x 16 q-rows.
// 128-key chunks (8 iters). Swapped QK^T (S^T[key,q], d padded 16->32) and
// swapped PV (O^T[d,q]). Q/K hi/lo bf16 (3-mfma), P/V single bf16.
__global__ __launch_bounds__(256) void attn_mfma_kernel(
    const u16* __restrict__ QH, const u16* __restrict__ QL,
    const u16* __restrict__ KH, const u16* __restrict__ KL,
    const u16* __restrict__ VB, u16* __restrict__ oh, u16* __restrict__ ol) {
  __shared__ u16 sKH[128 * 32];   // [key][32 d-padded] swizzled, hi (8KB)
  __shared__ u16 sKL[128 * 32];   // lo (8KB)
  __shared__ u16 sVT[16 * 128];   // [d][128 keys], 16B-chunk XOR swizzle (4KB)
  __shared__ u16 sP[4][16 * 128]; // per-wave P^T bounce [q][128 keys] (16KB)
  int t = threadIdx.x;
  int qt = blockIdx.x, h = blockIdx.y, b = blockIdx.z;
  int wid = t >> 6, lane = t & 63;
  int lr = lane & 15, g = lane >> 4;
  size_t base = ((size_t)(b * H_ + h)) * (N_ * HD_);
  int qrow = qt * 64 + wid * 16 + lr;

  // zero the d=16..31 pad chunks of sKH/sKL once (swizzle-consistent positions)
  {
    int plane = t >> 7, r = t & 127;
    u16* dst = (plane ? sKL : sKH) + r * 32;
    u16x8 z = {};
    *(u16x8*)(dst + ((2 ^ swz(r)) << 3)) = z;
    *(u16x8*)(dst + ((3 ^ swz(r)) << 3)) = z;
  }

  // Q fragments (held in registers): lane lr = q-col, g = d-slice (g>=2 zero)
  bf16x8 qfh = {}, qfl = {};
  if (g < 2) {
    size_t qi = base + (size_t)qrow * HD_ + g * 8;
    qfh = __builtin_bit_cast(bf16x8, *(const u16x8*)&QH[qi]);
    qfl = __builtin_bit_cast(bf16x8, *(const u16x8*)&QL[qi]);
  }

  f32x4 acc = {};
  float mrun = -1e30f, lrun = 0.f;
  u16* pw = &sP[wid][0];

  for (int ch = 0; ch < 8; ++ch) {
    int key0 = ch * 128;
    __syncthreads();
    // ---- stage K chunk (hi: t<128, lo: t>=128), 128 keys x 16 real d ----
    {
      int plane = t >> 7, id = t & 127;
      const u16* kbase = (plane ? KL : KH) + base;
      u16* dstb = plane ? sKL : sKH;
#pragma unroll
      for (int i = 0; i < 2; ++i) {
        int e = i * 128 + id;
        int r = e >> 1, gg2 = e & 1;
        *(u16x8*)&dstb[r * 32 + ((gg2 ^ swz(r)) << 3)] =
            *(const u16x8*)&kbase[(size_t)(key0 + r) * HD_ + gg2 * 8];
      }
    }
    // ---- stage V^T: [d][128 keys] via u16 scatter ----
#pragma unroll
    for (int i = 0; i < 2; ++i) {
      int e = i * 256 + t;
      int key = e >> 2, d0 = (e & 3) * 4;
      u16x4 vv = *(const u16x4*)&VB[base + (size_t)(key0 + key) * HD_ + d0];
#pragma unroll
      for (int jj = 0; jj < 4; ++jj) {
        int d = d0 + jj;
        sVT[d * 128 + (((key >> 3) ^ (d & 7)) << 3) + (key & 7)] = vv[jj];
      }
    }
    __syncthreads();

    // ---- QK^T: 8 key-subtiles, S^T[key,q], hi/lo 3-mfma ----
    f32x4 st[8];
#pragma unroll
    for (int t8 = 0; t8 < 8; ++t8) {
      bf16x8 kfh = ldfrag(sKH, t8 * 16 + lr, g);
      bf16x8 kfl = ldfrag(sKL, t8 * 16 + lr, g);
      f32x4 s = {};
      s = MFMA16(kfh, qfl, s);
      s = MFMA16(kfl, qfh, s);
      s = MFMA16(kfh, qfh, s);
      st[t8] = s;
    }

    // ---- online softmax: lane owns q=lr; keys split over 4 lanes (g) ----
    float cmax = -1e30f;
#pragma unroll
    for (int t8 = 0; t8 < 8; ++t8)
#pragma unroll
      for (int r = 0; r < 4; ++r) cmax = fmaxf(cmax, st[t8][r]);
    cmax = fmaxf(cmax, __shfl_xor(cmax, 16));
    cmax = fmaxf(cmax, __shfl_xor(cmax, 32));
    float mnew = fmaxf(mrun, cmax);
    float corr = __expf(mrun - mnew);
    float p[32];
    float psum = 0.f;
#pragma unroll
    for (int t8 = 0; t8 < 8; ++t8)
#pragma unroll
      for (int r = 0; r < 4; ++r) {
        float pv = __expf(st[t8][r] - mnew);
        p[t8 * 4 + r] = pv; psum += pv;
      }
    psum += __shfl_xor(psum, 16);
    psum += __shfl_xor(psum, 32);
    lrun = lrun * corr + psum;
    mrun = mnew;
#pragma unroll
    for (int r = 0; r < 4; ++r) acc[r] *= corr;

    // ---- pack P to bf16, bounce via per-wave LDS to re-group keys ----
#pragma unroll
    for (int t8 = 0; t8 < 8; ++t8) {
      unsigned w0 = (unsigned)bfbits(p[t8 * 4 + 0]) | ((unsigned)bfbits(p[t8 * 4 + 1]) << 16);
      unsigned w1 = (unsigned)bfbits(p[t8 * 4 + 2]) | ((unsigned)bfbits(p[t8 * 4 + 3]) << 16);
      int c = 2 * t8 + (g >> 1);
      int off = lr * 128 + ((c ^ (lr & 7)) << 3) + (g & 1) * 4;  // u16 units
      uint2 val; val.x = w0; val.y = w1;
      *(uint2*)&pw[off] = val;
    }
    // ---- PV: O^T += V^T-frag x P^T-frag, 4 key-subtiles of 32 ----
#pragma unroll
    for (int kk = 0; kk < 4; ++kk) {
      int off = lr * 128 + (((kk * 4 + g) ^ (lr & 7)) << 3);
      bf16x8 pb = __builtin_bit_cast(bf16x8, *(const u16x8*)&pw[off]);
      bf16x8 va = __builtin_bit_cast(bf16x8, *(const u16x8*)&sVT[off]);
      acc = MFMA16(va, pb, acc);
    }
  }

  // ---- epilogue: lane owns q=lr, d = 4g + reg ----
  float inv = 1.0f / lrun;
  size_t o = ((size_t)b * N_ + qrow) * C_ + h * HD_ + 4 * g;
  u16x4 vh, vl;
#pragma unroll
  for (int r = 0; r < 4; ++r) {
    u16 hh, ll; splitf(acc[r] * inv, hh, ll);
    vh[r] = hh; vl[r] = ll;
  }
  *(u16x4*)&oh[o] = vh;
  *(u16x4*)&ol[o] = vl;
}

// ---------------------------------------------------------------------------
extern "C" void kernel_launch(void* const* d_in, const int* in_sizes, int n_in,
                              void* d_out, int out_size, void* d_ws, size_t ws_size,
                              hipStream_t stream) {
  const float* x     = (const float*)d_in[0];
  const float* w1    = (const float*)d_in[1];
  const float* b1    = (const float*)d_in[2];
  const float* w2    = (const float*)d_in[3];
  const float* b2    = (const float*)d_in[4];
  const float* w3    = (const float*)d_in[5];
  const float* b3    = (const float*)d_in[6];
  const float* w_out = (const float*)d_in[7];
  float* out = (float*)d_out;

  // ---- workspace layout (byte offsets) ----
  char* ws = (char*)d_ws;
  u16* XPH = (u16*)(ws + 0);                    //  7,102,464 B
  u16* XPL = (u16*)(ws + 7102464);
  u16* W1H = (u16*)(ws + 14204928);             //  2,654,208 B
  u16* W1L = (u16*)(ws + 16859136);
  u16* W2H = (u16*)(ws + 19513344);             //  1,179,648 B
  u16* W2L = (u16*)(ws + 20692992);
  u16* W3H = (u16*)(ws + 21872640);             //    884,736 B
  u16* W3L = (u16*)(ws + 22757376);
  u16* WOH = (u16*)(ws + 23642112);             //     73,728 B
  u16* WOL = (u16*)(ws + 23715840);
  // Region A @23,789,568: a1 hi/lo -> a3 f32 -> o hi/lo
  u16*   A1H = (u16*)(ws + 23789568);
  u16*   A1L = (u16*)(ws + 48955392);
  float* A3  = (float*)(ws + 23789568);         // a1 dead
  u16*   OH  = (u16*)(ws + 23789568);           // a3 dead after gather
  u16*   OL  = (u16*)(ws + 36372480);
  // Region B @74,121,216: a2 hi/lo -> QH/QL/KH/KL/VB u16 (6,291,456 B each)
  u16*   A2H = (u16*)(ws + 74121216);
  u16*   A2L = (u16*)(ws + 99287040);
  u16*   QHb = (u16*)(ws + 74121216);           // a2 dead
  u16*   QLb = (u16*)(ws + 80412672);
  u16*   KHb = (u16*)(ws + 86704128);
  u16*   KLb = (u16*)(ws + 92995584);
  u16*   VBb = (u16*)(ws + 99287040);
  // total: 124,452,864 B

  // ---- pack inputs to bf16 hi/lo ----
  pack_x_kernel<<<dim3(1734), 256, 0, stream>>>(x, XPH, XPL);
  pack_w1_kernel<<<dim3(576), 256, 0, stream>>>(w1, W1H, W1L);
  pack_gen_kernel<<<dim3(288), 256, 0, stream>>>(w2, W2H, W2L, 73728);
  pack_gen_kernel<<<dim3(216), 256, 0, stream>>>(w3, W3H, W3L, 55296);
  pack_gen_kernel<<<dim3(18), 256, 0, stream>>>(w_out, WOH, WOL, 4608);

  // ---- main pipeline ----
  conv_mfma_kernel<<<dim3(8, 6, 16), 256, 0, stream>>>(XPH, XPL, W1H, W1L, b1, A1H, A1L);
  gemm_mfma_kernel<0, 128><<<dim3(8, 6, 16), 256, 0, stream>>>(
      W2H, W2L, b2, A1H, A1L, A2H, A2L, HID_, HID_);
  gemm_mfma_kernel<1, 64><<<dim3(8, 9, 16), 256, 0, stream>>>(
      W3H, W3L, b3, A2H, A2L, A3, nullptr, C3_, HID_);
  qkv_gather_kernel<<<dim3(12288), 256, 0, stream>>>(A3, x, QHb, QLb, KHb, KLb, VBb);
  attn_mfma_kernel<<<dim3(16, 12, 16), 256, 0, stream>>>(QHb, QLb, KHb, KLb, VBb, OH, OL);
  gemm_mfma_kernel<2, 64><<<dim3(8, 3, 16), 256, 0, stream>>>(
      WOH, WOL, nullptr, OH, OL, out, nullptr, C_, C_);
}